// Round 4
// baseline (622.765 us; speedup 1.0000x reference)
//
#include <hip/hip_runtime.h>

#define NN 50000
#define NE 1600000
#define IN_CH 128
#define HEADS 4
#define OUT_CH 32
#define HC 128                  // HEADS*OUT_CH
#define NEG_SLOPE 0.2f
#define EPS 1e-9f
#define NT 16                   // nodes per proj block
#define PAD 16                  // ints per node slot in deg/cursor (64B line)

#define PROJ_BLOCKS (NN / NT)                    // 3125
#define COUNT_BLOCKS ((NE / 4 + 255) / 256)      // 1563

__device__ __forceinline__ float leaky(float v) {
    return v >= 0.0f ? v : NEG_SLOPE * v;
}
__device__ __forceinline__ unsigned short f2bf(float f) {   // RNE bf16
    unsigned u = __float_as_uint(f);
    return (unsigned short)((u + 0x7fffu + ((u >> 16) & 1u)) >> 16);
}
__device__ __forceinline__ float bf2f(unsigned short b) {
    return __uint_as_float((unsigned)b << 16);
}

// ---------------------------------------------------------------- init ------
__global__ __launch_bounds__(256) void k_init(int* __restrict__ deg) {
    int i = blockIdx.x * 256 + threadIdx.x;
    if (i < NN * PAD) deg[i] = 0;
}

// --------------------------------------- fused projection+logits & count ----
// blocks [0, PROJ_BLOCKS): 256 threads; half = tid>>7 handles 8 nodes,
//   thread j = tid&127 owns output channel j.
// blocks [PROJ_BLOCKS, PROJ_BLOCKS+COUNT_BLOCKS): degree histogram, 4 edges/thread.
__global__ __launch_bounds__(256) void k_proj_count(
        const float* __restrict__ x, const float* __restrict__ W,
        const float* __restrict__ att_s, const float* __restrict__ att_d,
        unsigned short* __restrict__ h_bf,
        float* __restrict__ a_s, float* __restrict__ a_d,
        const int* __restrict__ ei, int* __restrict__ deg) {
    if (blockIdx.x >= PROJ_BLOCKS) {
        // ----- degree count: 4 edges per thread, int4 load ------------------
        int e0 = ((blockIdx.x - PROJ_BLOCKS) * 256 + threadIdx.x) * 4;
        if (e0 >= NE) return;
        const int4 d4 = *(const int4*)(ei + NE + e0);
        atomicAdd(&deg[d4.x * PAD], 1);
        atomicAdd(&deg[d4.y * PAD], 1);
        atomicAdd(&deg[d4.z * PAD], 1);
        atomicAdd(&deg[d4.w * PAD], 1);
        return;
    }
    // ----- projection ------------------------------------------------------
    __shared__ float xs[NT][IN_CH];
    const int tid = threadIdx.x;
    const int j = tid & 127;
    const int half = tid >> 7;          // 0 or 1
    const int n0 = blockIdx.x * NT;
#pragma unroll
    for (int t = 0; t < 8; ++t)
        xs[half * 8 + t][j] = x[(size_t)(n0 + half * 8 + t) * IN_CH + j];
    __syncthreads();

    float acc[8];
#pragma unroll
    for (int t = 0; t < 8; ++t) acc[t] = 0.0f;
    for (int k = 0; k < IN_CH; ++k) {
        const float wk = W[k * HC + j];
#pragma unroll
        for (int t = 0; t < 8; ++t)
            acc[t] = fmaf(xs[half * 8 + t][k], wk, acc[t]);
    }

    const float asj = att_s[j];
    const float adj = att_d[j];
#pragma unroll
    for (int t = 0; t < 8; ++t) {
        const int n = n0 + half * 8 + t;
        h_bf[(size_t)n * HC + j] = f2bf(acc[t]);
        float ps = acc[t] * asj;
        float pd = acc[t] * adj;
#pragma unroll
        for (int m = 16; m >= 1; m >>= 1) {
            ps += __shfl_xor(ps, m, 64);
            pd += __shfl_xor(pd, m, 64);
        }
        if ((j & 31) == 0) {
            a_s[n * HEADS + (j >> 5)] = ps;
            a_d[n * HEADS + (j >> 5)] = pd;
        }
    }
}

// ------------------------------------------------------- exclusive scan -----
__global__ __launch_bounds__(1024) void k_scan(const int* __restrict__ deg,
                                               int* __restrict__ row_ptr,
                                               int* __restrict__ cursor) {
    __shared__ int part[1024];
    const int tid = threadIdx.x;
    const int CHUNK = (NN + 1023) / 1024;          // 49
    const int base = tid * CHUNK;
    int sum = 0;
    for (int i = 0; i < CHUNK; ++i) {
        int idx = base + i;
        if (idx < NN) sum += deg[idx * PAD];
    }
    part[tid] = sum;
    __syncthreads();
    for (int off = 1; off < 1024; off <<= 1) {
        int v = 0;
        if (tid >= off) v = part[tid - off];
        __syncthreads();
        if (tid >= off) part[tid] += v;
        __syncthreads();
    }
    int run = part[tid] - sum;
    for (int i = 0; i < CHUNK; ++i) {
        int idx = base + i;
        if (idx < NN) {
            row_ptr[idx] = run;
            cursor[idx * PAD] = run;
            run += deg[idx * PAD];
        }
    }
    if (tid == 0) row_ptr[NN] = NE;
}

// ------------------------------------------------------------- CSR fill -----
// 4 edges per thread, int4 loads, padded cursor, nontemporal scatter store
__global__ __launch_bounds__(256) void k_fill(const int* __restrict__ ei,
                                              int* __restrict__ cursor,
                                              int* __restrict__ csr_src) {
    int e0 = (blockIdx.x * 256 + threadIdx.x) * 4;
    if (e0 >= NE) return;
    const int4 s4 = *(const int4*)(ei + e0);
    const int4 d4 = *(const int4*)(ei + NE + e0);
    int p0 = atomicAdd(&cursor[d4.x * PAD], 1);
    int p1 = atomicAdd(&cursor[d4.y * PAD], 1);
    int p2 = atomicAdd(&cursor[d4.z * PAD], 1);
    int p3 = atomicAdd(&cursor[d4.w * PAD], 1);
    __builtin_nontemporal_store(s4.x, &csr_src[p0]);
    __builtin_nontemporal_store(s4.y, &csr_src[p1]);
    __builtin_nontemporal_store(s4.z, &csr_src[p2]);
    __builtin_nontemporal_store(s4.w, &csr_src[p3]);
}

// ----------------------------------------------------- gather aggregation ---
// one wave per dst node; lane owns channels 2*lane, 2*lane+1
__global__ __launch_bounds__(256) void k_agg(const int* __restrict__ row_ptr,
                                             const int* __restrict__ csr_src,
                                             const unsigned short* __restrict__ h_bf,
                                             const float* __restrict__ a_s,
                                             const float* __restrict__ a_d,
                                             const float* __restrict__ bias,
                                             float* __restrict__ out) {
    const int n = blockIdx.x * 4 + (threadIdx.x >> 6);
    const int lane = threadIdx.x & 63;
    if (n >= NN) return;
    const int hd = lane >> 4;
    const int beg = row_ptr[n];
    const int end = row_ptr[n + 1];

    const float4 ad4 = *(const float4*)(a_d + n * 4);
    const float4 asn4 = *(const float4*)(a_s + n * 4);

    // ---- pass 1: per-head max (self-loop + incoming) ----------------------
    float4 mx4 = make_float4(leaky(asn4.x + ad4.x), leaky(asn4.y + ad4.y),
                             leaky(asn4.z + ad4.z), leaky(asn4.w + ad4.w));
    for (int i = beg + lane; i < end; i += 64) {
        int s = csr_src[i];
        const float4 as4 = *(const float4*)(a_s + s * 4);
        mx4.x = fmaxf(mx4.x, leaky(as4.x + ad4.x));
        mx4.y = fmaxf(mx4.y, leaky(as4.y + ad4.y));
        mx4.z = fmaxf(mx4.z, leaky(as4.z + ad4.z));
        mx4.w = fmaxf(mx4.w, leaky(as4.w + ad4.w));
    }
#pragma unroll
    for (int m = 32; m >= 1; m >>= 1) {
        mx4.x = fmaxf(mx4.x, __shfl_xor(mx4.x, m, 64));
        mx4.y = fmaxf(mx4.y, __shfl_xor(mx4.y, m, 64));
        mx4.z = fmaxf(mx4.z, __shfl_xor(mx4.z, m, 64));
        mx4.w = fmaxf(mx4.w, __shfl_xor(mx4.w, m, 64));
    }
    const float ad_h = hd == 0 ? ad4.x : hd == 1 ? ad4.y : hd == 2 ? ad4.z : ad4.w;
    const float mh   = hd == 0 ? mx4.x : hd == 1 ? mx4.y : hd == 2 ? mx4.z : mx4.w;
    const float as_h = hd == 0 ? asn4.x : hd == 1 ? asn4.y : hd == 2 ? asn4.z : asn4.w;

    // ---- pass 2: exp + weighted accumulate (division deferred) ------------
    float eself = __expf(leaky(as_h + ad_h) - mh);
    float denom = eself;
    const ushort2 hs = *(const ushort2*)(h_bf + (size_t)n * HC + 2 * lane);
    float acc0 = eself * bf2f(hs.x);
    float acc1 = eself * bf2f(hs.y);

    int s_next = (beg < end) ? csr_src[beg] : 0;
    for (int i = beg; i < end; ++i) {
        int s = s_next;
        if (i + 1 < end) s_next = csr_src[i + 1];
        float asv = a_s[s * 4 + hd];
        float ev = __expf(leaky(asv + ad_h) - mh);
        const ushort2 hv = *(const ushort2*)(h_bf + (size_t)s * HC + 2 * lane);
        denom += ev;
        acc0 = fmaf(ev, bf2f(hv.x), acc0);
        acc1 = fmaf(ev, bf2f(hv.y), acc1);
    }
    const float inv = 1.0f / (denom + EPS);
    out[(size_t)n * HC + 2 * lane]     = acc0 * inv + bias[2 * lane];
    out[(size_t)n * HC + 2 * lane + 1] = acc1 * inv + bias[2 * lane + 1];
}

// ---------------------------------------------------------------------------
extern "C" void kernel_launch(void* const* d_in, const int* in_sizes, int n_in,
                              void* d_out, int out_size, void* d_ws, size_t ws_size,
                              hipStream_t stream) {
    const float* x     = (const float*)d_in[0];
    const int*   ei    = (const int*)d_in[1];
    const float* W     = (const float*)d_in[2];
    const float* att_s = (const float*)d_in[3];
    const float* att_d = (const float*)d_in[4];
    const float* bias  = (const float*)d_in[5];
    float* out = (float*)d_out;

    char* ws = (char*)d_ws;
    int*   deg     = (int*)ws;    ws += (size_t)NN * PAD * 4;    // 3.2 MB padded
    int*   cursor  = (int*)ws;    ws += (size_t)NN * PAD * 4;    // 3.2 MB padded
    int*   row_ptr = (int*)ws;    ws += (size_t)(NN + 1) * 4;
    int*   csr_src = (int*)ws;    ws += (size_t)NE * 4;          // 6.4 MB
    unsigned short* h_bf = (unsigned short*)ws; ws += (size_t)NN * HC * 2; // 12.8 MB
    float* a_s     = (float*)ws;  ws += (size_t)NN * HEADS * 4;
    float* a_d     = (float*)ws;  ws += (size_t)NN * HEADS * 4;

    k_init      <<<(NN * PAD + 255) / 256, 256, 0, stream>>>(deg);
    k_proj_count<<<PROJ_BLOCKS + COUNT_BLOCKS, 256, 0, stream>>>(
        x, W, att_s, att_d, h_bf, a_s, a_d, ei, deg);
    k_scan      <<<1, 1024, 0, stream>>>(deg, row_ptr, cursor);
    k_fill      <<<COUNT_BLOCKS, 256, 0, stream>>>(ei, cursor, csr_src);
    k_agg       <<<(NN + 3) / 4, 256, 0, stream>>>(row_ptr, csr_src, h_bf, a_s, a_d, bias, out);
}

// Round 5
// 440.981 us; speedup vs baseline: 1.4122x; 1.4122x over previous
//
#include <hip/hip_runtime.h>

#define NN 50000
#define NE 1600000
#define IN_CH 128
#define HEADS 4
#define OUT_CH 32
#define HC 128                  // HEADS*OUT_CH
#define NEG_SLOPE 0.2f
#define EPS 1e-9f
#define NT 16                   // nodes per proj block
#define PAD 16                  // ints per node slot in deg/cursor (64B line)

#define PROJ_BLOCKS (NN / NT)                    // 3125
#define COUNT_BLOCKS ((NE / 4 + 255) / 256)      // 1563
#define NPB 256                                  // nodes per scan block
#define SCAN_BLOCKS ((NN + NPB - 1) / NPB)       // 196

__device__ __forceinline__ float leaky(float v) {
    return v >= 0.0f ? v : NEG_SLOPE * v;
}
__device__ __forceinline__ unsigned short f2bf(float f) {   // RNE bf16
    unsigned u = __float_as_uint(f);
    return (unsigned short)((u + 0x7fffu + ((u >> 16) & 1u)) >> 16);
}
__device__ __forceinline__ float bf2f(unsigned short b) {
    return __uint_as_float((unsigned)b << 16);
}

// ---------------------------------------------------------------- init ------
__global__ __launch_bounds__(256) void k_init(int* __restrict__ deg) {
    int i = blockIdx.x * 256 + threadIdx.x;
    if (i < NN * PAD) deg[i] = 0;
}

// --------------------------------------- fused projection+logits & count ----
__global__ __launch_bounds__(256) void k_proj_count(
        const float* __restrict__ x, const float* __restrict__ W,
        const float* __restrict__ att_s, const float* __restrict__ att_d,
        unsigned short* __restrict__ h_bf,
        float* __restrict__ a_s, float* __restrict__ a_d,
        const int* __restrict__ ei, int* __restrict__ deg) {
    if (blockIdx.x >= PROJ_BLOCKS) {
        int e0 = ((blockIdx.x - PROJ_BLOCKS) * 256 + threadIdx.x) * 4;
        if (e0 >= NE) return;
        const int4 d4 = *(const int4*)(ei + NE + e0);
        atomicAdd(&deg[d4.x * PAD], 1);
        atomicAdd(&deg[d4.y * PAD], 1);
        atomicAdd(&deg[d4.z * PAD], 1);
        atomicAdd(&deg[d4.w * PAD], 1);
        return;
    }
    __shared__ float xs[NT][IN_CH];
    const int tid = threadIdx.x;
    const int j = tid & 127;
    const int half = tid >> 7;
    const int n0 = blockIdx.x * NT;
#pragma unroll
    for (int t = 0; t < 8; ++t)
        xs[half * 8 + t][j] = x[(size_t)(n0 + half * 8 + t) * IN_CH + j];
    __syncthreads();

    float acc[8];
#pragma unroll
    for (int t = 0; t < 8; ++t) acc[t] = 0.0f;
    for (int k = 0; k < IN_CH; ++k) {
        const float wk = W[k * HC + j];
#pragma unroll
        for (int t = 0; t < 8; ++t)
            acc[t] = fmaf(xs[half * 8 + t][k], wk, acc[t]);
    }

    const float asj = att_s[j];
    const float adj = att_d[j];
#pragma unroll
    for (int t = 0; t < 8; ++t) {
        const int n = n0 + half * 8 + t;
        h_bf[(size_t)n * HC + j] = f2bf(acc[t]);
        float ps = acc[t] * asj;
        float pd = acc[t] * adj;
#pragma unroll
        for (int m = 16; m >= 1; m >>= 1) {
            ps += __shfl_xor(ps, m, 64);
            pd += __shfl_xor(pd, m, 64);
        }
        if ((j & 31) == 0) {
            a_s[n * HEADS + (j >> 5)] = ps;
            a_d[n * HEADS + (j >> 5)] = pd;
        }
    }
}

// --------------------------------------------- hierarchical scan, phase 1 ---
// per-block reduction of 256 padded degrees -> partial[b]
__global__ __launch_bounds__(256) void k_scan_part(const int* __restrict__ deg,
                                                   int* __restrict__ partial) {
    const int n = blockIdx.x * NPB + threadIdx.x;
    int v = (n < NN) ? deg[n * PAD] : 0;
#pragma unroll
    for (int m = 32; m >= 1; m >>= 1) v += __shfl_xor(v, m, 64);
    __shared__ int ws[4];
    if ((threadIdx.x & 63) == 0) ws[threadIdx.x >> 6] = v;
    __syncthreads();
    if (threadIdx.x == 0)
        partial[blockIdx.x] = ws[0] + ws[1] + ws[2] + ws[3];
}

// --------------------------------------------- hierarchical scan, phase 2 ---
// single block: exclusive scan of SCAN_BLOCKS partials (in place)
__global__ __launch_bounds__(256) void k_scan_top(int* __restrict__ partial,
                                                  int* __restrict__ row_ptr) {
    __shared__ int sh[256];
    const int tid = threadIdx.x;
    int v = (tid < SCAN_BLOCKS) ? partial[tid] : 0;
    sh[tid] = v;
    __syncthreads();
    for (int off = 1; off < 256; off <<= 1) {
        int t = 0;
        if (tid >= off) t = sh[tid - off];
        __syncthreads();
        if (tid >= off) sh[tid] += t;
        __syncthreads();
    }
    if (tid < SCAN_BLOCKS) partial[tid] = sh[tid] - v;   // exclusive
    if (tid == 0) row_ptr[NN] = NE;
}

// --------------------------------------------- hierarchical scan, phase 3 ---
// block-local exclusive scan + base -> row_ptr (compact) & cursor (padded)
__global__ __launch_bounds__(256) void k_scan_final(const int* __restrict__ deg,
                                                    const int* __restrict__ partial,
                                                    int* __restrict__ row_ptr,
                                                    int* __restrict__ cursor) {
    __shared__ int sh[256];
    const int tid = threadIdx.x;
    const int n = blockIdx.x * NPB + tid;
    int v = (n < NN) ? deg[n * PAD] : 0;
    sh[tid] = v;
    __syncthreads();
    for (int off = 1; off < 256; off <<= 1) {
        int t = 0;
        if (tid >= off) t = sh[tid - off];
        __syncthreads();
        if (tid >= off) sh[tid] += t;
        __syncthreads();
    }
    if (n < NN) {
        int pos = partial[blockIdx.x] + sh[tid] - v;     // exclusive
        row_ptr[n] = pos;
        cursor[n * PAD] = pos;
    }
}

// ------------------------------------------------------------- CSR fill -----
__global__ __launch_bounds__(256) void k_fill(const int* __restrict__ ei,
                                              int* __restrict__ cursor,
                                              int* __restrict__ csr_src) {
    int e0 = (blockIdx.x * 256 + threadIdx.x) * 4;
    if (e0 >= NE) return;
    const int4 s4 = *(const int4*)(ei + e0);
    const int4 d4 = *(const int4*)(ei + NE + e0);
    int p0 = atomicAdd(&cursor[d4.x * PAD], 1);
    int p1 = atomicAdd(&cursor[d4.y * PAD], 1);
    int p2 = atomicAdd(&cursor[d4.z * PAD], 1);
    int p3 = atomicAdd(&cursor[d4.w * PAD], 1);
    __builtin_nontemporal_store(s4.x, &csr_src[p0]);
    __builtin_nontemporal_store(s4.y, &csr_src[p1]);
    __builtin_nontemporal_store(s4.z, &csr_src[p2]);
    __builtin_nontemporal_store(s4.w, &csr_src[p3]);
}

// ----------------------------------------------------- gather aggregation ---
__global__ __launch_bounds__(256) void k_agg(const int* __restrict__ row_ptr,
                                             const int* __restrict__ csr_src,
                                             const unsigned short* __restrict__ h_bf,
                                             const float* __restrict__ a_s,
                                             const float* __restrict__ a_d,
                                             const float* __restrict__ bias,
                                             float* __restrict__ out) {
    const int n = blockIdx.x * 4 + (threadIdx.x >> 6);
    const int lane = threadIdx.x & 63;
    if (n >= NN) return;
    const int hd = lane >> 4;
    const int beg = row_ptr[n];
    const int end = row_ptr[n + 1];

    const float4 ad4 = *(const float4*)(a_d + n * 4);
    const float4 asn4 = *(const float4*)(a_s + n * 4);

    float4 mx4 = make_float4(leaky(asn4.x + ad4.x), leaky(asn4.y + ad4.y),
                             leaky(asn4.z + ad4.z), leaky(asn4.w + ad4.w));
    for (int i = beg + lane; i < end; i += 64) {
        int s = csr_src[i];
        const float4 as4 = *(const float4*)(a_s + s * 4);
        mx4.x = fmaxf(mx4.x, leaky(as4.x + ad4.x));
        mx4.y = fmaxf(mx4.y, leaky(as4.y + ad4.y));
        mx4.z = fmaxf(mx4.z, leaky(as4.z + ad4.z));
        mx4.w = fmaxf(mx4.w, leaky(as4.w + ad4.w));
    }
#pragma unroll
    for (int m = 32; m >= 1; m >>= 1) {
        mx4.x = fmaxf(mx4.x, __shfl_xor(mx4.x, m, 64));
        mx4.y = fmaxf(mx4.y, __shfl_xor(mx4.y, m, 64));
        mx4.z = fmaxf(mx4.z, __shfl_xor(mx4.z, m, 64));
        mx4.w = fmaxf(mx4.w, __shfl_xor(mx4.w, m, 64));
    }
    const float ad_h = hd == 0 ? ad4.x : hd == 1 ? ad4.y : hd == 2 ? ad4.z : ad4.w;
    const float mh   = hd == 0 ? mx4.x : hd == 1 ? mx4.y : hd == 2 ? mx4.z : mx4.w;
    const float as_h = hd == 0 ? asn4.x : hd == 1 ? asn4.y : hd == 2 ? asn4.z : asn4.w;

    float eself = __expf(leaky(as_h + ad_h) - mh);
    float denom = eself;
    const ushort2 hs = *(const ushort2*)(h_bf + (size_t)n * HC + 2 * lane);
    float acc0 = eself * bf2f(hs.x);
    float acc1 = eself * bf2f(hs.y);

    int s_next = (beg < end) ? csr_src[beg] : 0;
    for (int i = beg; i < end; ++i) {
        int s = s_next;
        if (i + 1 < end) s_next = csr_src[i + 1];
        float asv = a_s[s * 4 + hd];
        float ev = __expf(leaky(asv + ad_h) - mh);
        const ushort2 hv = *(const ushort2*)(h_bf + (size_t)s * HC + 2 * lane);
        denom += ev;
        acc0 = fmaf(ev, bf2f(hv.x), acc0);
        acc1 = fmaf(ev, bf2f(hv.y), acc1);
    }
    const float inv = 1.0f / (denom + EPS);
    out[(size_t)n * HC + 2 * lane]     = acc0 * inv + bias[2 * lane];
    out[(size_t)n * HC + 2 * lane + 1] = acc1 * inv + bias[2 * lane + 1];
}

// ---------------------------------------------------------------------------
extern "C" void kernel_launch(void* const* d_in, const int* in_sizes, int n_in,
                              void* d_out, int out_size, void* d_ws, size_t ws_size,
                              hipStream_t stream) {
    const float* x     = (const float*)d_in[0];
    const int*   ei    = (const int*)d_in[1];
    const float* W     = (const float*)d_in[2];
    const float* att_s = (const float*)d_in[3];
    const float* att_d = (const float*)d_in[4];
    const float* bias  = (const float*)d_in[5];
    float* out = (float*)d_out;

    char* ws = (char*)d_ws;
    int*   deg     = (int*)ws;    ws += (size_t)NN * PAD * 4;    // 3.2 MB padded
    int*   cursor  = (int*)ws;    ws += (size_t)NN * PAD * 4;    // 3.2 MB padded
    int*   row_ptr = (int*)ws;    ws += (size_t)(NN + 1) * 4;
    int*   partial = (int*)ws;    ws += (size_t)SCAN_BLOCKS * 4;
    int*   csr_src = (int*)ws;    ws += (size_t)NE * 4;          // 6.4 MB
    unsigned short* h_bf = (unsigned short*)ws; ws += (size_t)NN * HC * 2; // 12.8 MB
    float* a_s     = (float*)ws;  ws += (size_t)NN * HEADS * 4;
    float* a_d     = (float*)ws;  ws += (size_t)NN * HEADS * 4;

    k_init      <<<(NN * PAD + 255) / 256, 256, 0, stream>>>(deg);
    k_proj_count<<<PROJ_BLOCKS + COUNT_BLOCKS, 256, 0, stream>>>(
        x, W, att_s, att_d, h_bf, a_s, a_d, ei, deg);
    k_scan_part <<<SCAN_BLOCKS, 256, 0, stream>>>(deg, partial);
    k_scan_top  <<<1, 256, 0, stream>>>(partial, row_ptr);
    k_scan_final<<<SCAN_BLOCKS, 256, 0, stream>>>(deg, partial, row_ptr, cursor);
    k_fill      <<<COUNT_BLOCKS, 256, 0, stream>>>(ei, cursor, csr_src);
    k_agg       <<<(NN + 3) / 4, 256, 0, stream>>>(row_ptr, csr_src, h_bf, a_s, a_d, bias, out);
}

// Round 6
// 335.040 us; speedup vs baseline: 1.8588x; 1.3162x over previous
//
#include <hip/hip_runtime.h>

#define NN 50000
#define NE 1600000
#define IN_CH 128
#define HEADS 4
#define OUT_CH 32
#define HC 128                  // HEADS*OUT_CH
#define NEG_SLOPE 0.2f
#define EPS 1e-9f
#define NT 16                   // nodes per proj block
#define PAD 16                  // ints per node slot in deg (64B line)

#define PROJ_BLOCKS (NN / NT)                    // 3125
#define COUNT_BLOCKS ((NE / 4 + 255) / 256)      // 1563
#define NPB 256                                  // nodes per scan block
#define SCAN_BLOCKS ((NN + NPB - 1) / NPB)       // 196
#define NGROUP 8                                 // XCD-affine fill groups
#define DPG (NN / NGROUP)                        // 6250 dst nodes per group
#define FILL_BPG ((NE / 8 + 255) / 256)          // 782 blocks per group

__device__ __forceinline__ float leaky(float v) {
    return v >= 0.0f ? v : NEG_SLOPE * v;
}
__device__ __forceinline__ unsigned short f2bf(float f) {   // RNE bf16
    unsigned u = __float_as_uint(f);
    return (unsigned short)((u + 0x7fffu + ((u >> 16) & 1u)) >> 16);
}
__device__ __forceinline__ float bf2f(unsigned short b) {
    return __uint_as_float((unsigned)b << 16);
}

// ---------------------------------------------------------------- init ------
__global__ __launch_bounds__(256) void k_init(int* __restrict__ deg) {
    int i = blockIdx.x * 256 + threadIdx.x;
    if (i < NN * PAD) deg[i] = 0;
}

// ------------------------- fused projection+logits & count-with-rank --------
// blocks [0, PROJ_BLOCKS): projection (256 thr, 16 nodes).
// blocks [PROJ_BLOCKS, +COUNT_BLOCKS): degree histogram; the atomic's return
// value is the edge's rank within its dst — stored coalesced for k_fill.
__global__ __launch_bounds__(256) void k_proj_count(
        const float* __restrict__ x, const float* __restrict__ W,
        const float* __restrict__ att_s, const float* __restrict__ att_d,
        unsigned short* __restrict__ h_bf,
        float* __restrict__ a_s, float* __restrict__ a_d,
        const int* __restrict__ ei, int* __restrict__ deg,
        int* __restrict__ rank) {
    if (blockIdx.x >= PROJ_BLOCKS) {
        int e0 = ((blockIdx.x - PROJ_BLOCKS) * 256 + threadIdx.x) * 4;
        if (e0 >= NE) return;
        const int4 d4 = *(const int4*)(ei + NE + e0);
        int4 r4;
        r4.x = atomicAdd(&deg[d4.x * PAD], 1);
        r4.y = atomicAdd(&deg[d4.y * PAD], 1);
        r4.z = atomicAdd(&deg[d4.z * PAD], 1);
        r4.w = atomicAdd(&deg[d4.w * PAD], 1);
        *(int4*)(rank + e0) = r4;
        return;
    }
    __shared__ float xs[NT][IN_CH];
    const int tid = threadIdx.x;
    const int j = tid & 127;
    const int half = tid >> 7;
    const int n0 = blockIdx.x * NT;
#pragma unroll
    for (int t = 0; t < 8; ++t)
        xs[half * 8 + t][j] = x[(size_t)(n0 + half * 8 + t) * IN_CH + j];
    __syncthreads();

    float acc[8];
#pragma unroll
    for (int t = 0; t < 8; ++t) acc[t] = 0.0f;
    for (int k = 0; k < IN_CH; ++k) {
        const float wk = W[k * HC + j];
#pragma unroll
        for (int t = 0; t < 8; ++t)
            acc[t] = fmaf(xs[half * 8 + t][k], wk, acc[t]);
    }

    const float asj = att_s[j];
    const float adj = att_d[j];
#pragma unroll
    for (int t = 0; t < 8; ++t) {
        const int n = n0 + half * 8 + t;
        h_bf[(size_t)n * HC + j] = f2bf(acc[t]);
        float ps = acc[t] * asj;
        float pd = acc[t] * adj;
#pragma unroll
        for (int m = 16; m >= 1; m >>= 1) {
            ps += __shfl_xor(ps, m, 64);
            pd += __shfl_xor(pd, m, 64);
        }
        if ((j & 31) == 0) {
            a_s[n * HEADS + (j >> 5)] = ps;
            a_d[n * HEADS + (j >> 5)] = pd;
        }
    }
}

// --------------------------------------------- hierarchical scan, phase 1 ---
__global__ __launch_bounds__(256) void k_scan_part(const int* __restrict__ deg,
                                                   int* __restrict__ partial) {
    const int n = blockIdx.x * NPB + threadIdx.x;
    int v = (n < NN) ? deg[n * PAD] : 0;
#pragma unroll
    for (int m = 32; m >= 1; m >>= 1) v += __shfl_xor(v, m, 64);
    __shared__ int ws[4];
    if ((threadIdx.x & 63) == 0) ws[threadIdx.x >> 6] = v;
    __syncthreads();
    if (threadIdx.x == 0)
        partial[blockIdx.x] = ws[0] + ws[1] + ws[2] + ws[3];
}

// --------------------------------------------- hierarchical scan, phase 2 ---
__global__ __launch_bounds__(256) void k_scan_top(int* __restrict__ partial,
                                                  int* __restrict__ row_ptr) {
    __shared__ int sh[256];
    const int tid = threadIdx.x;
    int v = (tid < SCAN_BLOCKS) ? partial[tid] : 0;
    sh[tid] = v;
    __syncthreads();
    for (int off = 1; off < 256; off <<= 1) {
        int t = 0;
        if (tid >= off) t = sh[tid - off];
        __syncthreads();
        if (tid >= off) sh[tid] += t;
        __syncthreads();
    }
    if (tid < SCAN_BLOCKS) partial[tid] = sh[tid] - v;   // exclusive
    if (tid == 0) row_ptr[NN] = NE;
}

// --------------------------------------------- hierarchical scan, phase 3 ---
__global__ __launch_bounds__(256) void k_scan_final(const int* __restrict__ deg,
                                                    const int* __restrict__ partial,
                                                    int* __restrict__ row_ptr) {
    __shared__ int sh[256];
    const int tid = threadIdx.x;
    const int n = blockIdx.x * NPB + tid;
    int v = (n < NN) ? deg[n * PAD] : 0;
    sh[tid] = v;
    __syncthreads();
    for (int off = 1; off < 256; off <<= 1) {
        int t = 0;
        if (tid >= off) t = sh[tid - off];
        __syncthreads();
        if (tid >= off) sh[tid] += t;
        __syncthreads();
    }
    if (n < NN) row_ptr[n] = partial[blockIdx.x] + sh[tid] - v;   // exclusive
}

// ------------------------------------------------------------- CSR fill -----
// Atomic-free: slot = row_ptr[dst] + rank[e]. XCD-affine: group g = blk&7
// (round-robin XCD dispatch) handles only dst in [g*DPG, (g+1)*DPG) so its
// scattered stores land in an ~800KB window that lives in its own L2 and
// coalesces into full lines before writeback. 8 edges per thread.
__global__ __launch_bounds__(256) void k_fill(const int* __restrict__ ei,
                                              const int* __restrict__ rank,
                                              const int* __restrict__ row_ptr,
                                              int* __restrict__ csr_src) {
    const int g = blockIdx.x & (NGROUP - 1);
    const int bg = blockIdx.x >> 3;
    const int e0 = (bg * 256 + (int)threadIdx.x) * 8;
    if (e0 >= NE) return;
    const int lo = g * DPG;
    const int4 d0 = *(const int4*)(ei + NE + e0);
    const int4 d1 = *(const int4*)(ei + NE + e0 + 4);
    const int4 s0 = *(const int4*)(ei + e0);
    const int4 s1 = *(const int4*)(ei + e0 + 4);
    const int4 r0 = *(const int4*)(rank + e0);
    const int4 r1 = *(const int4*)(rank + e0 + 4);
    const int d[8] = {d0.x, d0.y, d0.z, d0.w, d1.x, d1.y, d1.z, d1.w};
    const int s[8] = {s0.x, s0.y, s0.z, s0.w, s1.x, s1.y, s1.z, s1.w};
    const int r[8] = {r0.x, r0.y, r0.z, r0.w, r1.x, r1.y, r1.z, r1.w};
#pragma unroll
    for (int k = 0; k < 8; ++k) {
        if ((unsigned)(d[k] - lo) < (unsigned)DPG)
            csr_src[row_ptr[d[k]] + r[k]] = s[k];
    }
}

// ----------------------------------------------------- gather aggregation ---
__global__ __launch_bounds__(256) void k_agg(const int* __restrict__ row_ptr,
                                             const int* __restrict__ csr_src,
                                             const unsigned short* __restrict__ h_bf,
                                             const float* __restrict__ a_s,
                                             const float* __restrict__ a_d,
                                             const float* __restrict__ bias,
                                             float* __restrict__ out) {
    const int n = blockIdx.x * 4 + (threadIdx.x >> 6);
    const int lane = threadIdx.x & 63;
    if (n >= NN) return;
    const int hd = lane >> 4;
    const int beg = row_ptr[n];
    const int end = row_ptr[n + 1];

    const float4 ad4 = *(const float4*)(a_d + n * 4);
    const float4 asn4 = *(const float4*)(a_s + n * 4);

    float4 mx4 = make_float4(leaky(asn4.x + ad4.x), leaky(asn4.y + ad4.y),
                             leaky(asn4.z + ad4.z), leaky(asn4.w + ad4.w));
    for (int i = beg + lane; i < end; i += 64) {
        int s = csr_src[i];
        const float4 as4 = *(const float4*)(a_s + s * 4);
        mx4.x = fmaxf(mx4.x, leaky(as4.x + ad4.x));
        mx4.y = fmaxf(mx4.y, leaky(as4.y + ad4.y));
        mx4.z = fmaxf(mx4.z, leaky(as4.z + ad4.z));
        mx4.w = fmaxf(mx4.w, leaky(as4.w + ad4.w));
    }
#pragma unroll
    for (int m = 32; m >= 1; m >>= 1) {
        mx4.x = fmaxf(mx4.x, __shfl_xor(mx4.x, m, 64));
        mx4.y = fmaxf(mx4.y, __shfl_xor(mx4.y, m, 64));
        mx4.z = fmaxf(mx4.z, __shfl_xor(mx4.z, m, 64));
        mx4.w = fmaxf(mx4.w, __shfl_xor(mx4.w, m, 64));
    }
    const float ad_h = hd == 0 ? ad4.x : hd == 1 ? ad4.y : hd == 2 ? ad4.z : ad4.w;
    const float mh   = hd == 0 ? mx4.x : hd == 1 ? mx4.y : hd == 2 ? mx4.z : mx4.w;
    const float as_h = hd == 0 ? asn4.x : hd == 1 ? asn4.y : hd == 2 ? asn4.z : asn4.w;

    float eself = __expf(leaky(as_h + ad_h) - mh);
    float denom = eself;
    const ushort2 hs = *(const ushort2*)(h_bf + (size_t)n * HC + 2 * lane);
    float acc0 = eself * bf2f(hs.x);
    float acc1 = eself * bf2f(hs.y);

    int s_next = (beg < end) ? csr_src[beg] : 0;
    for (int i = beg; i < end; ++i) {
        int s = s_next;
        if (i + 1 < end) s_next = csr_src[i + 1];
        float asv = a_s[s * 4 + hd];
        float ev = __expf(leaky(asv + ad_h) - mh);
        const ushort2 hv = *(const ushort2*)(h_bf + (size_t)s * HC + 2 * lane);
        denom += ev;
        acc0 = fmaf(ev, bf2f(hv.x), acc0);
        acc1 = fmaf(ev, bf2f(hv.y), acc1);
    }
    const float inv = 1.0f / (denom + EPS);
    out[(size_t)n * HC + 2 * lane]     = acc0 * inv + bias[2 * lane];
    out[(size_t)n * HC + 2 * lane + 1] = acc1 * inv + bias[2 * lane + 1];
}

// ---------------------------------------------------------------------------
extern "C" void kernel_launch(void* const* d_in, const int* in_sizes, int n_in,
                              void* d_out, int out_size, void* d_ws, size_t ws_size,
                              hipStream_t stream) {
    const float* x     = (const float*)d_in[0];
    const int*   ei    = (const int*)d_in[1];
    const float* W     = (const float*)d_in[2];
    const float* att_s = (const float*)d_in[3];
    const float* att_d = (const float*)d_in[4];
    const float* bias  = (const float*)d_in[5];
    float* out = (float*)d_out;

    char* ws = (char*)d_ws;
    int*   deg     = (int*)ws;    ws += (size_t)NN * PAD * 4;    // 3.2 MB padded
    int*   rank    = (int*)ws;    ws += (size_t)NE * 4;          // 6.4 MB
    int*   row_ptr = (int*)ws;    ws += (size_t)(NN + 1) * 4;
    int*   partial = (int*)ws;    ws += (size_t)SCAN_BLOCKS * 4;
    int*   csr_src = (int*)ws;    ws += (size_t)NE * 4;          // 6.4 MB
    unsigned short* h_bf = (unsigned short*)ws; ws += (size_t)NN * HC * 2; // 12.8 MB
    float* a_s     = (float*)ws;  ws += (size_t)NN * HEADS * 4;
    float* a_d     = (float*)ws;  ws += (size_t)NN * HEADS * 4;

    k_init      <<<(NN * PAD + 255) / 256, 256, 0, stream>>>(deg);
    k_proj_count<<<PROJ_BLOCKS + COUNT_BLOCKS, 256, 0, stream>>>(
        x, W, att_s, att_d, h_bf, a_s, a_d, ei, deg, rank);
    k_scan_part <<<SCAN_BLOCKS, 256, 0, stream>>>(deg, partial);
    k_scan_top  <<<1, 256, 0, stream>>>(partial, row_ptr);
    k_scan_final<<<SCAN_BLOCKS, 256, 0, stream>>>(deg, partial, row_ptr);
    k_fill      <<<FILL_BPG * NGROUP, 256, 0, stream>>>(ei, rank, row_ptr, csr_src);
    k_agg       <<<(NN + 3) / 4, 256, 0, stream>>>(row_ptr, csr_src, h_bf, a_s, a_d, bias, out);
}

// Round 7
// 299.925 us; speedup vs baseline: 2.0764x; 1.1171x over previous
//
#include <hip/hip_runtime.h>

#define NN 50000
#define NE 1600000
#define IN_CH 128
#define HEADS 4
#define OUT_CH 32
#define HC 128                  // HEADS*OUT_CH
#define NEG_SLOPE 0.2f
#define EPS 1e-9f
#define NT 16                   // nodes per proj block
#define PAD 16                  // ints per node slot in deg (64B line)

#define PROJ_BLOCKS (NN / NT)                    // 3125
#define COUNT_BLOCKS ((NE / 4 + 255) / 256)      // 1563
#define NPB 256                                  // nodes per scan block
#define SCAN_BLOCKS ((NN + NPB - 1) / NPB)       // 196
#define NGROUP 8                                 // XCD-affine fill groups
#define DPG (NN / NGROUP)                        // 6250 dst nodes per group
#define FILL_BPG ((NE / 8 + 255) / 256)          // 782 blocks per group

#define ENC_NEG_INF 0x007FFFFFu

__device__ __forceinline__ float leaky(float v) {
    return v >= 0.0f ? v : NEG_SLOPE * v;
}
__device__ __forceinline__ unsigned short f2bf(float f) {   // RNE bf16
    unsigned u = __float_as_uint(f);
    return (unsigned short)((u + 0x7fffu + ((u >> 16) & 1u)) >> 16);
}
__device__ __forceinline__ float bf2f(unsigned short b) {
    return __uint_as_float((unsigned)b << 16);
}
__device__ __forceinline__ unsigned int fenc(float f) {     // order-preserving
    unsigned int u = __float_as_uint(f);
    return (u & 0x80000000u) ? ~u : (u | 0x80000000u);
}
__device__ __forceinline__ float fdec(unsigned int u) {
    return (u & 0x80000000u) ? __uint_as_float(u & 0x7fffffffu)
                             : __uint_as_float(~u);
}

// ---------------------------------------------------------------- init ------
__global__ __launch_bounds__(256) void k_init(int* __restrict__ deg,
                                              unsigned int* __restrict__ gmax) {
    int i = blockIdx.x * 256 + threadIdx.x;
    if (i < NN * PAD) deg[i] = 0;
    if (i < HEADS) gmax[i] = ENC_NEG_INF;
}

// ------------------------- fused projection+logits & count-with-rank --------
__global__ __launch_bounds__(256) void k_proj_count(
        const float* __restrict__ x, const float* __restrict__ W,
        const float* __restrict__ att_s, const float* __restrict__ att_d,
        unsigned short* __restrict__ h_bf,
        float* __restrict__ a_s, float* __restrict__ a_d,
        const int* __restrict__ ei, int* __restrict__ deg,
        int* __restrict__ rank) {
    if (blockIdx.x >= PROJ_BLOCKS) {
        int e0 = ((blockIdx.x - PROJ_BLOCKS) * 256 + threadIdx.x) * 4;
        if (e0 >= NE) return;
        const int4 d4 = *(const int4*)(ei + NE + e0);
        int4 r4;
        r4.x = atomicAdd(&deg[d4.x * PAD], 1);
        r4.y = atomicAdd(&deg[d4.y * PAD], 1);
        r4.z = atomicAdd(&deg[d4.z * PAD], 1);
        r4.w = atomicAdd(&deg[d4.w * PAD], 1);
        *(int4*)(rank + e0) = r4;
        return;
    }
    __shared__ float xs[NT][IN_CH];
    const int tid = threadIdx.x;
    const int j = tid & 127;
    const int half = tid >> 7;
    const int n0 = blockIdx.x * NT;
#pragma unroll
    for (int t = 0; t < 8; ++t)
        xs[half * 8 + t][j] = x[(size_t)(n0 + half * 8 + t) * IN_CH + j];
    __syncthreads();

    float acc[8];
#pragma unroll
    for (int t = 0; t < 8; ++t) acc[t] = 0.0f;
    for (int k = 0; k < IN_CH; ++k) {
        const float wk = W[k * HC + j];
#pragma unroll
        for (int t = 0; t < 8; ++t)
            acc[t] = fmaf(xs[half * 8 + t][k], wk, acc[t]);
    }

    const float asj = att_s[j];
    const float adj = att_d[j];
#pragma unroll
    for (int t = 0; t < 8; ++t) {
        const int n = n0 + half * 8 + t;
        h_bf[(size_t)n * HC + j] = f2bf(acc[t]);
        float ps = acc[t] * asj;
        float pd = acc[t] * adj;
#pragma unroll
        for (int m = 16; m >= 1; m >>= 1) {
            ps += __shfl_xor(ps, m, 64);
            pd += __shfl_xor(pd, m, 64);
        }
        if ((j & 31) == 0) {
            a_s[n * HEADS + (j >> 5)] = ps;
            a_d[n * HEADS + (j >> 5)] = pd;
        }
    }
}

// ------------------ hierarchical scan, phase 1 (+ global a_s max) -----------
__global__ __launch_bounds__(256) void k_scan_part(const int* __restrict__ deg,
                                                   const float* __restrict__ a_s,
                                                   int* __restrict__ partial,
                                                   unsigned int* __restrict__ gmax) {
    const int n = blockIdx.x * NPB + threadIdx.x;
    int v = 0;
    float4 m4 = make_float4(-1e30f, -1e30f, -1e30f, -1e30f);
    if (n < NN) {
        v = deg[n * PAD];
        m4 = *(const float4*)(a_s + n * 4);
    }
#pragma unroll
    for (int m = 32; m >= 1; m >>= 1) {
        v += __shfl_xor(v, m, 64);
        m4.x = fmaxf(m4.x, __shfl_xor(m4.x, m, 64));
        m4.y = fmaxf(m4.y, __shfl_xor(m4.y, m, 64));
        m4.z = fmaxf(m4.z, __shfl_xor(m4.z, m, 64));
        m4.w = fmaxf(m4.w, __shfl_xor(m4.w, m, 64));
    }
    __shared__ int ws[4];
    __shared__ float wm[4][4];
    const int wv = threadIdx.x >> 6;
    if ((threadIdx.x & 63) == 0) {
        ws[wv] = v;
        wm[wv][0] = m4.x; wm[wv][1] = m4.y; wm[wv][2] = m4.z; wm[wv][3] = m4.w;
    }
    __syncthreads();
    if (threadIdx.x == 0)
        partial[blockIdx.x] = ws[0] + ws[1] + ws[2] + ws[3];
    if (threadIdx.x < 4) {
        float mm = fmaxf(fmaxf(wm[0][threadIdx.x], wm[1][threadIdx.x]),
                         fmaxf(wm[2][threadIdx.x], wm[3][threadIdx.x]));
        atomicMax(&gmax[threadIdx.x], fenc(mm));
    }
}

// --------------------------------------------- hierarchical scan, phase 2 ---
__global__ __launch_bounds__(256) void k_scan_top(int* __restrict__ partial,
                                                  int* __restrict__ row_ptr) {
    __shared__ int sh[256];
    const int tid = threadIdx.x;
    int v = (tid < SCAN_BLOCKS) ? partial[tid] : 0;
    sh[tid] = v;
    __syncthreads();
    for (int off = 1; off < 256; off <<= 1) {
        int t = 0;
        if (tid >= off) t = sh[tid - off];
        __syncthreads();
        if (tid >= off) sh[tid] += t;
        __syncthreads();
    }
    if (tid < SCAN_BLOCKS) partial[tid] = sh[tid] - v;   // exclusive
    if (tid == 0) row_ptr[NN] = NE;
}

// --------------------------------------------- hierarchical scan, phase 3 ---
__global__ __launch_bounds__(256) void k_scan_final(const int* __restrict__ deg,
                                                    const int* __restrict__ partial,
                                                    int* __restrict__ row_ptr) {
    __shared__ int sh[256];
    const int tid = threadIdx.x;
    const int n = blockIdx.x * NPB + tid;
    int v = (n < NN) ? deg[n * PAD] : 0;
    sh[tid] = v;
    __syncthreads();
    for (int off = 1; off < 256; off <<= 1) {
        int t = 0;
        if (tid >= off) t = sh[tid - off];
        __syncthreads();
        if (tid >= off) sh[tid] += t;
        __syncthreads();
    }
    if (n < NN) row_ptr[n] = partial[blockIdx.x] + sh[tid] - v;   // exclusive
}

// ------------------------------------------------------------- CSR fill -----
__global__ __launch_bounds__(256) void k_fill(const int* __restrict__ ei,
                                              const int* __restrict__ rank,
                                              const int* __restrict__ row_ptr,
                                              int* __restrict__ csr_src) {
    const int g = blockIdx.x & (NGROUP - 1);
    const int bg = blockIdx.x >> 3;
    const int e0 = (bg * 256 + (int)threadIdx.x) * 8;
    if (e0 >= NE) return;
    const int lo = g * DPG;
    const int4 d0 = *(const int4*)(ei + NE + e0);
    const int4 d1 = *(const int4*)(ei + NE + e0 + 4);
    const int4 s0 = *(const int4*)(ei + e0);
    const int4 s1 = *(const int4*)(ei + e0 + 4);
    const int4 r0 = *(const int4*)(rank + e0);
    const int4 r1 = *(const int4*)(rank + e0 + 4);
    const int d[8] = {d0.x, d0.y, d0.z, d0.w, d1.x, d1.y, d1.z, d1.w};
    const int s[8] = {s0.x, s0.y, s0.z, s0.w, s1.x, s1.y, s1.z, s1.w};
    const int r[8] = {r0.x, r0.y, r0.z, r0.w, r1.x, r1.y, r1.z, r1.w};
#pragma unroll
    for (int k = 0; k < 8; ++k) {
        if ((unsigned)(d[k] - lo) < (unsigned)DPG)
            csr_src[row_ptr[d[k]] + r[k]] = s[k];
    }
}

// ----------------------------------------------------- gather aggregation ---
// one wave per dst node; each 32-lane half owns alternate edges; lane owns
// 4 channels (ushort4). Softmax shifted by global upper bound -> no max pass.
__global__ __launch_bounds__(256) void k_agg(const int* __restrict__ row_ptr,
                                             const int* __restrict__ csr_src,
                                             const unsigned short* __restrict__ h_bf,
                                             const float* __restrict__ a_s,
                                             const float* __restrict__ a_d,
                                             const unsigned int* __restrict__ gmax,
                                             const float* __restrict__ bias,
                                             float* __restrict__ out) {
    const int n = blockIdx.x * 4 + (threadIdx.x >> 6);
    const int lane = threadIdx.x & 63;
    if (n >= NN) return;
    const int half = lane >> 5;
    const int hl = lane & 31;                     // owns channels 4*hl..4*hl+3
    const int hd = hl >> 3;                       // head of those channels
    const int beg = row_ptr[n];
    const int end = row_ptr[n + 1];

    const float ad_h = a_d[n * 4 + hd];
    const float bound = leaky(fdec(gmax[hd]) + ad_h);   // >= every edge score

    // self-loop at weight 0.5 per half (cross-half combine restores 1x)
    float ev = 0.5f * __expf(leaky(a_s[n * 4 + hd] + ad_h) - bound);
    float denom = ev;
    const ushort4 hs = *(const ushort4*)(h_bf + (size_t)n * HC + 4 * hl);
    float acc0 = ev * bf2f(hs.x);
    float acc1 = ev * bf2f(hs.y);
    float acc2 = ev * bf2f(hs.z);
    float acc3 = ev * bf2f(hs.w);

    int i = beg + half;
    int s_next = (i < end) ? csr_src[i] : 0;
    for (; i < end; i += 2) {
        const int s = s_next;
        if (i + 2 < end) s_next = csr_src[i + 2];
        const float e = __expf(leaky(a_s[s * 4 + hd] + ad_h) - bound);
        const ushort4 hv = *(const ushort4*)(h_bf + (size_t)s * HC + 4 * hl);
        denom += e;
        acc0 = fmaf(e, bf2f(hv.x), acc0);
        acc1 = fmaf(e, bf2f(hv.y), acc1);
        acc2 = fmaf(e, bf2f(hv.z), acc2);
        acc3 = fmaf(e, bf2f(hv.w), acc3);
    }
    acc0 += __shfl_xor(acc0, 32, 64);
    acc1 += __shfl_xor(acc1, 32, 64);
    acc2 += __shfl_xor(acc2, 32, 64);
    acc3 += __shfl_xor(acc3, 32, 64);
    denom += __shfl_xor(denom, 32, 64);

    if (half == 0) {
        const float inv = 1.0f / (denom + EPS);
        const float4 b4 = *(const float4*)(bias + 4 * hl);
        float4 o;
        o.x = acc0 * inv + b4.x;
        o.y = acc1 * inv + b4.y;
        o.z = acc2 * inv + b4.z;
        o.w = acc3 * inv + b4.w;
        *(float4*)(out + (size_t)n * HC + 4 * hl) = o;
    }
}

// ---------------------------------------------------------------------------
extern "C" void kernel_launch(void* const* d_in, const int* in_sizes, int n_in,
                              void* d_out, int out_size, void* d_ws, size_t ws_size,
                              hipStream_t stream) {
    const float* x     = (const float*)d_in[0];
    const int*   ei    = (const int*)d_in[1];
    const float* W     = (const float*)d_in[2];
    const float* att_s = (const float*)d_in[3];
    const float* att_d = (const float*)d_in[4];
    const float* bias  = (const float*)d_in[5];
    float* out = (float*)d_out;

    char* ws = (char*)d_ws;
    int*   deg     = (int*)ws;    ws += (size_t)NN * PAD * 4;    // 3.2 MB padded
    int*   rank    = (int*)ws;    ws += (size_t)NE * 4;          // 6.4 MB
    int*   row_ptr = (int*)ws;    ws += (size_t)(NN + 1) * 4;
    unsigned int* gmax = (unsigned int*)ws; ws += 64;
    int*   partial = (int*)ws;    ws += (size_t)SCAN_BLOCKS * 4;
    int*   csr_src = (int*)ws;    ws += (size_t)NE * 4;          // 6.4 MB
    unsigned short* h_bf = (unsigned short*)ws; ws += (size_t)NN * HC * 2; // 12.8 MB
    float* a_s     = (float*)ws;  ws += (size_t)NN * HEADS * 4;
    float* a_d     = (float*)ws;  ws += (size_t)NN * HEADS * 4;

    k_init      <<<(NN * PAD + 255) / 256, 256, 0, stream>>>(deg, gmax);
    k_proj_count<<<PROJ_BLOCKS + COUNT_BLOCKS, 256, 0, stream>>>(
        x, W, att_s, att_d, h_bf, a_s, a_d, ei, deg, rank);
    k_scan_part <<<SCAN_BLOCKS, 256, 0, stream>>>(deg, a_s, partial, gmax);
    k_scan_top  <<<1, 256, 0, stream>>>(partial, row_ptr);
    k_scan_final<<<SCAN_BLOCKS, 256, 0, stream>>>(deg, partial, row_ptr);
    k_fill      <<<FILL_BPG * NGROUP, 256, 0, stream>>>(ei, rank, row_ptr, csr_src);
    k_agg       <<<(NN + 3) / 4, 256, 0, stream>>>(row_ptr, csr_src, h_bf, a_s, a_d,
                                                   gmax, bias, out);
}

// Round 8
// 294.969 us; speedup vs baseline: 2.1113x; 1.0168x over previous
//
#include <hip/hip_runtime.h>

#define NN 50000
#define NE 1600000
#define IN_CH 128
#define HEADS 4
#define OUT_CH 32
#define HC 128                  // HEADS*OUT_CH
#define NEG_SLOPE 0.2f
#define EPS 1e-9f
#define PAD 16                  // ints per node slot in deg (64B line)

#define COUNT_BLOCKS ((NE / 4 + 255) / 256)      // 1563
#define LOGIT_BLOCKS (NN / 4)                    // 12500
#define NPB 256                                  // nodes per scan block
#define SCAN_BLOCKS ((NN + NPB - 1) / NPB)       // 196
#define NGROUP 8                                 // XCD-affine fill groups
#define DPG (NN / NGROUP)                        // 6250 dst nodes per group
#define FILL_BPG ((NE / 8 + 255) / 256)          // 782 blocks per group
#define ROWS_PB 64                               // rows per MFMA proj block
#define PROJ_BLOCKS ((NN + ROWS_PB - 1) / ROWS_PB)   // 782
#define XPITCH 136                               // LDS x row pitch (shorts)

#define ENC_NEG_INF 0x007FFFFFu

using bf16x8 = __attribute__((ext_vector_type(8))) short;
using f32x4  = __attribute__((ext_vector_type(4))) float;

__device__ __forceinline__ float leaky(float v) {
    return v >= 0.0f ? v : NEG_SLOPE * v;
}
__device__ __forceinline__ unsigned short f2bf(float f) {   // RNE bf16
    unsigned u = __float_as_uint(f);
    return (unsigned short)((u + 0x7fffu + ((u >> 16) & 1u)) >> 16);
}
__device__ __forceinline__ float bf2f(unsigned short b) {
    return __uint_as_float((unsigned)b << 16);
}
__device__ __forceinline__ unsigned int fenc(float f) {     // order-preserving
    unsigned int u = __float_as_uint(f);
    return (u & 0x80000000u) ? ~u : (u | 0x80000000u);
}
__device__ __forceinline__ float fdec(unsigned int u) {
    return (u & 0x80000000u) ? __uint_as_float(u & 0x7fffffffu)
                             : __uint_as_float(~u);
}

// ----------------------------- init: deg=0, gmax, W -> Wt_bf (transposed) ---
__global__ __launch_bounds__(256) void k_init(int* __restrict__ deg,
                                              unsigned int* __restrict__ gmax,
                                              const float* __restrict__ W,
                                              unsigned short* __restrict__ Wt_bf) {
    int i = blockIdx.x * 256 + threadIdx.x;
    if (i < NN * PAD) deg[i] = 0;
    if (i < HEADS) gmax[i] = ENC_NEG_INF;
    if (i < IN_CH * HC) {
        int k = i >> 7, n = i & 127;
        Wt_bf[n * IN_CH + k] = f2bf(W[i]);
    }
}

// --------------------------------------------------- MFMA projection --------
// 4 waves/block, wave w computes rows [n0+16w, n0+16w+16) x all 128 cols.
// A (x rows) staged in LDS as bf16, pitch 136; B from global Wt_bf (32KB, L1).
__global__ __launch_bounds__(256) void k_proj(const float* __restrict__ x,
                                              const unsigned short* __restrict__ Wt_bf,
                                              unsigned short* __restrict__ h_bf) {
    __shared__ short xs[ROWS_PB * XPITCH];
    const int tid = threadIdx.x;
    const int n0 = blockIdx.x * ROWS_PB;

    // stage 64 rows of x as bf16 (float4 loads, 2-way-free LDS writes)
#pragma unroll
    for (int it = 0; it < 8; ++it) {
        const int idx = it * 256 + tid;          // float4 index
        const int row = idx >> 5;                // 32 float4 per row
        const int k4 = idx & 31;
        float4 v = make_float4(0.f, 0.f, 0.f, 0.f);
        if (n0 + row < NN) v = *(const float4*)(x + (size_t)(n0 + row) * IN_CH + k4 * 4);
        short* p = &xs[row * XPITCH + k4 * 4];
        p[0] = (short)f2bf(v.x); p[1] = (short)f2bf(v.y);
        p[2] = (short)f2bf(v.z); p[3] = (short)f2bf(v.w);
    }
    __syncthreads();

    const int wave = tid >> 6;
    const int lane = tid & 63;
    const int quad = lane >> 4;
    const int m16 = lane & 15;
    const int wrow = wave * 16;

    // A fragments: A[m=lane&15][k=quad*8+j], one per 32-wide k-step
    bf16x8 a[4];
#pragma unroll
    for (int ks = 0; ks < 4; ++ks)
        a[ks] = *(const bf16x8*)&xs[(wrow + m16) * XPITCH + ks * 32 + quad * 8];

    const int row_base = n0 + wrow + quad * 4;
#pragma unroll
    for (int ct = 0; ct < 8; ++ct) {
        // B fragments: B[k=quad*8+j][n=lane&15] from Wt_bf[n][k]
        const unsigned short* wb = Wt_bf + (size_t)(ct * 16 + m16) * IN_CH + quad * 8;
        bf16x8 b0 = *(const bf16x8*)(wb);
        bf16x8 b1 = *(const bf16x8*)(wb + 32);
        bf16x8 b2 = *(const bf16x8*)(wb + 64);
        bf16x8 b3 = *(const bf16x8*)(wb + 96);
        f32x4 acc = {0.f, 0.f, 0.f, 0.f};
        acc = __builtin_amdgcn_mfma_f32_16x16x32_bf16(a[0], b0, acc, 0, 0, 0);
        acc = __builtin_amdgcn_mfma_f32_16x16x32_bf16(a[1], b1, acc, 0, 0, 0);
        acc = __builtin_amdgcn_mfma_f32_16x16x32_bf16(a[2], b2, acc, 0, 0, 0);
        acc = __builtin_amdgcn_mfma_f32_16x16x32_bf16(a[3], b3, acc, 0, 0, 0);
        // D: col=lane&15, row=quad*4+reg
#pragma unroll
        for (int r = 0; r < 4; ++r) {
            const int n = row_base + r;
            if (n < NN) h_bf[(size_t)n * HC + ct * 16 + m16] = f2bf(acc[r]);
        }
    }
}

// ------------------------- fused logits (from h_bf) & count-with-rank -------
__global__ __launch_bounds__(256) void k_logits_count(
        const unsigned short* __restrict__ h_bf,
        const float* __restrict__ att_s, const float* __restrict__ att_d,
        float* __restrict__ a_s, float* __restrict__ a_d,
        const int* __restrict__ ei, int* __restrict__ deg,
        int* __restrict__ rank) {
    if (blockIdx.x >= LOGIT_BLOCKS) {
        int e0 = ((blockIdx.x - LOGIT_BLOCKS) * 256 + threadIdx.x) * 4;
        if (e0 >= NE) return;
        const int4 d4 = *(const int4*)(ei + NE + e0);
        int4 r4;
        r4.x = atomicAdd(&deg[d4.x * PAD], 1);
        r4.y = atomicAdd(&deg[d4.y * PAD], 1);
        r4.z = atomicAdd(&deg[d4.z * PAD], 1);
        r4.w = atomicAdd(&deg[d4.w * PAD], 1);
        *(int4*)(rank + e0) = r4;
        return;
    }
    const int n = blockIdx.x * 4 + (threadIdx.x >> 6);
    const int lane = threadIdx.x & 63;             // owns ch 2l, 2l+1
    const ushort2 hv = *(const ushort2*)(h_bf + (size_t)n * HC + 2 * lane);
    const float h0 = bf2f(hv.x), h1 = bf2f(hv.y);
    float ps = h0 * att_s[2 * lane] + h1 * att_s[2 * lane + 1];
    float pd = h0 * att_d[2 * lane] + h1 * att_d[2 * lane + 1];
#pragma unroll
    for (int m = 8; m >= 1; m >>= 1) {
        ps += __shfl_xor(ps, m, 64);
        pd += __shfl_xor(pd, m, 64);
    }
    if ((lane & 15) == 0) {
        a_s[n * HEADS + (lane >> 4)] = ps;
        a_d[n * HEADS + (lane >> 4)] = pd;
    }
}

// ------------------ hierarchical scan, phase 1 (+ global a_s max) -----------
__global__ __launch_bounds__(256) void k_scan_part(const int* __restrict__ deg,
                                                   const float* __restrict__ a_s,
                                                   int* __restrict__ partial,
                                                   unsigned int* __restrict__ gmax) {
    const int n = blockIdx.x * NPB + threadIdx.x;
    int v = 0;
    float4 m4 = make_float4(-1e30f, -1e30f, -1e30f, -1e30f);
    if (n < NN) {
        v = deg[n * PAD];
        m4 = *(const float4*)(a_s + n * 4);
    }
#pragma unroll
    for (int m = 32; m >= 1; m >>= 1) {
        v += __shfl_xor(v, m, 64);
        m4.x = fmaxf(m4.x, __shfl_xor(m4.x, m, 64));
        m4.y = fmaxf(m4.y, __shfl_xor(m4.y, m, 64));
        m4.z = fmaxf(m4.z, __shfl_xor(m4.z, m, 64));
        m4.w = fmaxf(m4.w, __shfl_xor(m4.w, m, 64));
    }
    __shared__ int ws[4];
    __shared__ float wm[4][4];
    const int wv = threadIdx.x >> 6;
    if ((threadIdx.x & 63) == 0) {
        ws[wv] = v;
        wm[wv][0] = m4.x; wm[wv][1] = m4.y; wm[wv][2] = m4.z; wm[wv][3] = m4.w;
    }
    __syncthreads();
    if (threadIdx.x == 0)
        partial[blockIdx.x] = ws[0] + ws[1] + ws[2] + ws[3];
    if (threadIdx.x < 4) {
        float mm = fmaxf(fmaxf(wm[0][threadIdx.x], wm[1][threadIdx.x]),
                         fmaxf(wm[2][threadIdx.x], wm[3][threadIdx.x]));
        atomicMax(&gmax[threadIdx.x], fenc(mm));
    }
}

// --------------------------------------------- hierarchical scan, phase 2 ---
__global__ __launch_bounds__(256) void k_scan_top(int* __restrict__ partial,
                                                  int* __restrict__ row_ptr) {
    __shared__ int sh[256];
    const int tid = threadIdx.x;
    int v = (tid < SCAN_BLOCKS) ? partial[tid] : 0;
    sh[tid] = v;
    __syncthreads();
    for (int off = 1; off < 256; off <<= 1) {
        int t = 0;
        if (tid >= off) t = sh[tid - off];
        __syncthreads();
        if (tid >= off) sh[tid] += t;
        __syncthreads();
    }
    if (tid < SCAN_BLOCKS) partial[tid] = sh[tid] - v;   // exclusive
    if (tid == 0) row_ptr[NN] = NE;
}

// --------------------------------------------- hierarchical scan, phase 3 ---
__global__ __launch_bounds__(256) void k_scan_final(const int* __restrict__ deg,
                                                    const int* __restrict__ partial,
                                                    int* __restrict__ row_ptr) {
    __shared__ int sh[256];
    const int tid = threadIdx.x;
    const int n = blockIdx.x * NPB + tid;
    int v = (n < NN) ? deg[n * PAD] : 0;
    sh[tid] = v;
    __syncthreads();
    for (int off = 1; off < 256; off <<= 1) {
        int t = 0;
        if (tid >= off) t = sh[tid - off];
        __syncthreads();
        if (tid >= off) sh[tid] += t;
        __syncthreads();
    }
    if (n < NN) row_ptr[n] = partial[blockIdx.x] + sh[tid] - v;   // exclusive
}

// ------------------------------------------------------------- CSR fill -----
__global__ __launch_bounds__(256) void k_fill(const int* __restrict__ ei,
                                              const int* __restrict__ rank,
                                              const int* __restrict__ row_ptr,
                                              int* __restrict__ csr_src) {
    const int g = blockIdx.x & (NGROUP - 1);
    const int bg = blockIdx.x >> 3;
    const int e0 = (bg * 256 + (int)threadIdx.x) * 8;
    if (e0 >= NE) return;
    const int lo = g * DPG;
    const int4 d0 = *(const int4*)(ei + NE + e0);
    const int4 d1 = *(const int4*)(ei + NE + e0 + 4);
    const int4 s0 = *(const int4*)(ei + e0);
    const int4 s1 = *(const int4*)(ei + e0 + 4);
    const int4 r0 = *(const int4*)(rank + e0);
    const int4 r1 = *(const int4*)(rank + e0 + 4);
    const int d[8] = {d0.x, d0.y, d0.z, d0.w, d1.x, d1.y, d1.z, d1.w};
    const int s[8] = {s0.x, s0.y, s0.z, s0.w, s1.x, s1.y, s1.z, s1.w};
    const int r[8] = {r0.x, r0.y, r0.z, r0.w, r1.x, r1.y, r1.z, r1.w};
#pragma unroll
    for (int k = 0; k < 8; ++k) {
        if ((unsigned)(d[k] - lo) < (unsigned)DPG)
            csr_src[row_ptr[d[k]] + r[k]] = s[k];
    }
}

// ----------------------------------------------------- gather aggregation ---
__global__ __launch_bounds__(256) void k_agg(const int* __restrict__ row_ptr,
                                             const int* __restrict__ csr_src,
                                             const unsigned short* __restrict__ h_bf,
                                             const float* __restrict__ a_s,
                                             const float* __restrict__ a_d,
                                             const unsigned int* __restrict__ gmax,
                                             const float* __restrict__ bias,
                                             float* __restrict__ out) {
    const int n = blockIdx.x * 4 + (threadIdx.x >> 6);
    const int lane = threadIdx.x & 63;
    if (n >= NN) return;
    const int half = lane >> 5;
    const int hl = lane & 31;                     // owns channels 4*hl..4*hl+3
    const int hd = hl >> 3;                       // head of those channels
    const int beg = row_ptr[n];
    const int end = row_ptr[n + 1];

    const float ad_h = a_d[n * 4 + hd];
    const float bound = leaky(fdec(gmax[hd]) + ad_h);   // >= every edge score

    float ev = 0.5f * __expf(leaky(a_s[n * 4 + hd] + ad_h) - bound);
    float denom = ev;
    const ushort4 hs = *(const ushort4*)(h_bf + (size_t)n * HC + 4 * hl);
    float acc0 = ev * bf2f(hs.x);
    float acc1 = ev * bf2f(hs.y);
    float acc2 = ev * bf2f(hs.z);
    float acc3 = ev * bf2f(hs.w);

    int i = beg + half;
    int s_next = (i < end) ? csr_src[i] : 0;
    for (; i < end; i += 2) {
        const int s = s_next;
        if (i + 2 < end) s_next = csr_src[i + 2];
        const float e = __expf(leaky(a_s[s * 4 + hd] + ad_h) - bound);
        const ushort4 hv = *(const ushort4*)(h_bf + (size_t)s * HC + 4 * hl);
        denom += e;
        acc0 = fmaf(e, bf2f(hv.x), acc0);
        acc1 = fmaf(e, bf2f(hv.y), acc1);
        acc2 = fmaf(e, bf2f(hv.z), acc2);
        acc3 = fmaf(e, bf2f(hv.w), acc3);
    }
    acc0 += __shfl_xor(acc0, 32, 64);
    acc1 += __shfl_xor(acc1, 32, 64);
    acc2 += __shfl_xor(acc2, 32, 64);
    acc3 += __shfl_xor(acc3, 32, 64);
    denom += __shfl_xor(denom, 32, 64);

    if (half == 0) {
        const float inv = 1.0f / (denom + EPS);
        const float4 b4 = *(const float4*)(bias + 4 * hl);
        float4 o;
        o.x = acc0 * inv + b4.x;
        o.y = acc1 * inv + b4.y;
        o.z = acc2 * inv + b4.z;
        o.w = acc3 * inv + b4.w;
        *(float4*)(out + (size_t)n * HC + 4 * hl) = o;
    }
}

// ---------------------------------------------------------------------------
extern "C" void kernel_launch(void* const* d_in, const int* in_sizes, int n_in,
                              void* d_out, int out_size, void* d_ws, size_t ws_size,
                              hipStream_t stream) {
    const float* x     = (const float*)d_in[0];
    const int*   ei    = (const int*)d_in[1];
    const float* W     = (const float*)d_in[2];
    const float* att_s = (const float*)d_in[3];
    const float* att_d = (const float*)d_in[4];
    const float* bias  = (const float*)d_in[5];
    float* out = (float*)d_out;

    char* ws = (char*)d_ws;
    int*   deg     = (int*)ws;    ws += (size_t)NN * PAD * 4;    // 3.2 MB padded
    int*   rank    = (int*)ws;    ws += (size_t)NE * 4;          // 6.4 MB
    int*   row_ptr = (int*)ws;    ws += 200016;                  // (NN+1) ints, 16B-rounded
    unsigned int* gmax = (unsigned int*)ws; ws += 64;
    int*   partial = (int*)ws;    ws += (size_t)SCAN_BLOCKS * 4; // 784 B
    int*   csr_src = (int*)ws;    ws += (size_t)NE * 4;          // 6.4 MB
    unsigned short* h_bf = (unsigned short*)ws; ws += (size_t)NN * HC * 2; // 12.8 MB
    float* a_s     = (float*)ws;  ws += (size_t)NN * HEADS * 4;
    float* a_d     = (float*)ws;  ws += (size_t)NN * HEADS * 4;
    unsigned short* Wt_bf = (unsigned short*)ws; ws += (size_t)IN_CH * HC * 2; // 32 KB

    k_init        <<<(NN * PAD + 255) / 256, 256, 0, stream>>>(deg, gmax, W, Wt_bf);
    k_proj        <<<PROJ_BLOCKS, 256, 0, stream>>>(x, Wt_bf, h_bf);
    k_logits_count<<<LOGIT_BLOCKS + COUNT_BLOCKS, 256, 0, stream>>>(
        h_bf, att_s, att_d, a_s, a_d, ei, deg, rank);
    k_scan_part   <<<SCAN_BLOCKS, 256, 0, stream>>>(deg, a_s, partial, gmax);
    k_scan_top    <<<1, 256, 0, stream>>>(partial, row_ptr);
    k_scan_final  <<<SCAN_BLOCKS, 256, 0, stream>>>(deg, partial, row_ptr);
    k_fill        <<<FILL_BPG * NGROUP, 256, 0, stream>>>(ei, rank, row_ptr, csr_src);
    k_agg         <<<(NN + 3) / 4, 256, 0, stream>>>(row_ptr, csr_src, h_bf, a_s, a_d,
                                                     gmax, bias, out);
}

// Round 9
// 275.900 us; speedup vs baseline: 2.2572x; 1.0691x over previous
//
#include <hip/hip_runtime.h>

#define NN 50000
#define NE 1600000
#define IN_CH 128
#define HEADS 4
#define OUT_CH 32
#define HC 128                  // HEADS*OUT_CH
#define NEG_SLOPE 0.2f
#define EPS 1e-9f
#define PAD 16                  // ints per node slot in deg (64B line)

#define COUNT_BLOCKS ((NE / 4 + 255) / 256)      // 1563
#define NPB 256                                  // nodes per scan block
#define SCAN_BLOCKS ((NN + NPB - 1) / NPB)       // 196
#define NGROUP 4                                 // L2-affine fill groups
#define DPG (NN / NGROUP)                        // 12500 dst nodes per group
#define FILL_BPG ((NE / 8 + 255) / 256)          // 782 blocks per group
#define ROWS_PB 64                               // rows per MFMA proj block
#define PROJ_BLOCKS ((NN + ROWS_PB - 1) / ROWS_PB)   // 782
#define XPITCH 136                               // LDS x row pitch (shorts)

#define ENC_NEG_INF 0x007FFFFFu

using bf16x8 = __attribute__((ext_vector_type(8))) short;
using f32x4  = __attribute__((ext_vector_type(4))) float;
using u16x8  = __attribute__((ext_vector_type(8))) unsigned short;

__device__ __forceinline__ float leaky(float v) {
    return v >= 0.0f ? v : NEG_SLOPE * v;
}
__device__ __forceinline__ unsigned short f2bf(float f) {   // RNE bf16
    unsigned u = __float_as_uint(f);
    return (unsigned short)((u + 0x7fffu + ((u >> 16) & 1u)) >> 16);
}
__device__ __forceinline__ float bf2f(unsigned short b) {
    return __uint_as_float((unsigned)b << 16);
}
__device__ __forceinline__ unsigned int fenc(float f) {     // order-preserving
    unsigned int u = __float_as_uint(f);
    return (u & 0x80000000u) ? ~u : (u | 0x80000000u);
}
__device__ __forceinline__ float fdec(unsigned int u) {
    return (u & 0x80000000u) ? __uint_as_float(u & 0x7fffffffu)
                             : __uint_as_float(~u);
}

// ----------------------------- init: gmax + W -> Wt_bf (transposed) ---------
__global__ __launch_bounds__(256) void k_init(unsigned int* __restrict__ gmax,
                                              const float* __restrict__ W,
                                              unsigned short* __restrict__ Wt_bf) {
    int i = blockIdx.x * 256 + threadIdx.x;
    if (i < HEADS) gmax[i] = ENC_NEG_INF;
    if (i < IN_CH * HC) {
        int k = i >> 7, n = i & 127;
        Wt_bf[n * IN_CH + k] = f2bf(W[i]);
    }
}

// ----------------- MFMA projection (+fused logits) & count-with-rank --------
// blocks [0, PROJ_BLOCKS): 4 waves, wave w rows [n0+16w, n0+16w+16).
// A (x rows) LDS bf16 pitch 136; B from global Wt_bf (32KB, L1/L2).
// Logits a_s/a_d computed from fp32 accumulators (head = ct>>1).
// blocks [PROJ_BLOCKS, +COUNT_BLOCKS): degree histogram with rank capture.
__global__ __launch_bounds__(256) void k_proj_count(
        const float* __restrict__ x,
        const unsigned short* __restrict__ Wt_bf,
        const float* __restrict__ att_s, const float* __restrict__ att_d,
        unsigned short* __restrict__ h_bf,
        float* __restrict__ a_s, float* __restrict__ a_d,
        const int* __restrict__ ei, int* __restrict__ deg,
        int* __restrict__ rank) {
    if (blockIdx.x >= PROJ_BLOCKS) {
        int e0 = ((blockIdx.x - PROJ_BLOCKS) * 256 + threadIdx.x) * 4;
        if (e0 >= NE) return;
        const int4 d4 = *(const int4*)(ei + NE + e0);
        int4 r4;
        r4.x = atomicAdd(&deg[d4.x * PAD], 1);
        r4.y = atomicAdd(&deg[d4.y * PAD], 1);
        r4.z = atomicAdd(&deg[d4.z * PAD], 1);
        r4.w = atomicAdd(&deg[d4.w * PAD], 1);
        *(int4*)(rank + e0) = r4;
        return;
    }
    __shared__ short xs[ROWS_PB * XPITCH];
    const int tid = threadIdx.x;
    const int n0 = blockIdx.x * ROWS_PB;

#pragma unroll
    for (int it = 0; it < 8; ++it) {
        const int idx = it * 256 + tid;          // float4 index
        const int row = idx >> 5;                // 32 float4 per row
        const int k4 = idx & 31;
        float4 v = make_float4(0.f, 0.f, 0.f, 0.f);
        if (n0 + row < NN) v = *(const float4*)(x + (size_t)(n0 + row) * IN_CH + k4 * 4);
        short* p = &xs[row * XPITCH + k4 * 4];
        p[0] = (short)f2bf(v.x); p[1] = (short)f2bf(v.y);
        p[2] = (short)f2bf(v.z); p[3] = (short)f2bf(v.w);
    }
    __syncthreads();

    const int wave = tid >> 6;
    const int lane = tid & 63;
    const int quad = lane >> 4;
    const int m16 = lane & 15;
    const int wrow = wave * 16;

    bf16x8 a[4];
#pragma unroll
    for (int ks = 0; ks < 4; ++ks)
        a[ks] = *(const bf16x8*)&xs[(wrow + m16) * XPITCH + ks * 32 + quad * 8];

    const int row_base = n0 + wrow + quad * 4;
#pragma unroll
    for (int hh = 0; hh < 4; ++hh) {
        float psh[4] = {0.f, 0.f, 0.f, 0.f};
        float pdh[4] = {0.f, 0.f, 0.f, 0.f};
#pragma unroll
        for (int c2 = 0; c2 < 2; ++c2) {
            const int ct = hh * 2 + c2;
            const unsigned short* wb = Wt_bf + (size_t)(ct * 16 + m16) * IN_CH + quad * 8;
            bf16x8 b0 = *(const bf16x8*)(wb);
            bf16x8 b1 = *(const bf16x8*)(wb + 32);
            bf16x8 b2 = *(const bf16x8*)(wb + 64);
            bf16x8 b3 = *(const bf16x8*)(wb + 96);
            f32x4 acc = {0.f, 0.f, 0.f, 0.f};
            acc = __builtin_amdgcn_mfma_f32_16x16x32_bf16(a[0], b0, acc, 0, 0, 0);
            acc = __builtin_amdgcn_mfma_f32_16x16x32_bf16(a[1], b1, acc, 0, 0, 0);
            acc = __builtin_amdgcn_mfma_f32_16x16x32_bf16(a[2], b2, acc, 0, 0, 0);
            acc = __builtin_amdgcn_mfma_f32_16x16x32_bf16(a[3], b3, acc, 0, 0, 0);
            const int col = ct * 16 + m16;
            const float asv = att_s[col];
            const float adv = att_d[col];
#pragma unroll
            for (int r = 0; r < 4; ++r) {
                const int n = row_base + r;
                if (n < NN) h_bf[(size_t)n * HC + col] = f2bf(acc[r]);
                psh[r] = fmaf(acc[r], asv, psh[r]);
                pdh[r] = fmaf(acc[r], adv, pdh[r]);
            }
        }
        // reduce over the 16 m16 lanes (stay within quad)
#pragma unroll
        for (int mk = 1; mk <= 8; mk <<= 1) {
#pragma unroll
            for (int r = 0; r < 4; ++r) {
                psh[r] += __shfl_xor(psh[r], mk, 64);
                pdh[r] += __shfl_xor(pdh[r], mk, 64);
            }
        }
        if (m16 == 0) {
#pragma unroll
            for (int r = 0; r < 4; ++r) {
                const int n = row_base + r;
                if (n < NN) {
                    a_s[n * HEADS + hh] = psh[r];
                    a_d[n * HEADS + hh] = pdh[r];
                }
            }
        }
    }
}

// ------------------ hierarchical scan, phase 1 (+ global a_s max) -----------
__global__ __launch_bounds__(256) void k_scan_part(const int* __restrict__ deg,
                                                   const float* __restrict__ a_s,
                                                   int* __restrict__ partial,
                                                   unsigned int* __restrict__ gmax) {
    const int n = blockIdx.x * NPB + threadIdx.x;
    int v = 0;
    float4 m4 = make_float4(-1e30f, -1e30f, -1e30f, -1e30f);
    if (n < NN) {
        v = deg[n * PAD];
        m4 = *(const float4*)(a_s + n * 4);
    }
#pragma unroll
    for (int m = 32; m >= 1; m >>= 1) {
        v += __shfl_xor(v, m, 64);
        m4.x = fmaxf(m4.x, __shfl_xor(m4.x, m, 64));
        m4.y = fmaxf(m4.y, __shfl_xor(m4.y, m, 64));
        m4.z = fmaxf(m4.z, __shfl_xor(m4.z, m, 64));
        m4.w = fmaxf(m4.w, __shfl_xor(m4.w, m, 64));
    }
    __shared__ int ws[4];
    __shared__ float wm[4][4];
    const int wv = threadIdx.x >> 6;
    if ((threadIdx.x & 63) == 0) {
        ws[wv] = v;
        wm[wv][0] = m4.x; wm[wv][1] = m4.y; wm[wv][2] = m4.z; wm[wv][3] = m4.w;
    }
    __syncthreads();
    if (threadIdx.x == 0)
        partial[blockIdx.x] = ws[0] + ws[1] + ws[2] + ws[3];
    if (threadIdx.x < 4) {
        float mm = fmaxf(fmaxf(wm[0][threadIdx.x], wm[1][threadIdx.x]),
                         fmaxf(wm[2][threadIdx.x], wm[3][threadIdx.x]));
        atomicMax(&gmax[threadIdx.x], fenc(mm));
    }
}

// --------------------------------------------- hierarchical scan, phase 2 ---
__global__ __launch_bounds__(256) void k_scan_top(int* __restrict__ partial,
                                                  int* __restrict__ row_ptr) {
    __shared__ int sh[256];
    const int tid = threadIdx.x;
    int v = (tid < SCAN_BLOCKS) ? partial[tid] : 0;
    sh[tid] = v;
    __syncthreads();
    for (int off = 1; off < 256; off <<= 1) {
        int t = 0;
        if (tid >= off) t = sh[tid - off];
        __syncthreads();
        if (tid >= off) sh[tid] += t;
        __syncthreads();
    }
    if (tid < SCAN_BLOCKS) partial[tid] = sh[tid] - v;   // exclusive
    if (tid == 0) row_ptr[NN] = NE;
}

// --------------------------------------------- hierarchical scan, phase 3 ---
__global__ __launch_bounds__(256) void k_scan_final(const int* __restrict__ deg,
                                                    const int* __restrict__ partial,
                                                    int* __restrict__ row_ptr) {
    __shared__ int sh[256];
    const int tid = threadIdx.x;
    const int n = blockIdx.x * NPB + tid;
    int v = (n < NN) ? deg[n * PAD] : 0;
    sh[tid] = v;
    __syncthreads();
    for (int off = 1; off < 256; off <<= 1) {
        int t = 0;
        if (tid >= off) t = sh[tid - off];
        __syncthreads();
        if (tid >= off) sh[tid] += t;
        __syncthreads();
    }
    if (n < NN) row_ptr[n] = partial[blockIdx.x] + sh[tid] - v;   // exclusive
}

// ------------------------------------------------------------- CSR fill -----
// Atomic-free: slot = row_ptr[dst] + rank[e]. Group g = blk&3 writes only
// dst in [g*DPG,(g+1)*DPG) so stores coalesce in a ~1.6MB L2-resident window.
__global__ __launch_bounds__(256) void k_fill(const int* __restrict__ ei,
                                              const int* __restrict__ rank,
                                              const int* __restrict__ row_ptr,
                                              int* __restrict__ csr_src) {
    const int g = blockIdx.x & (NGROUP - 1);
    const int bg = blockIdx.x >> 2;
    const int e0 = (bg * 256 + (int)threadIdx.x) * 8;
    if (e0 >= NE) return;
    const int lo = g * DPG;
    const int4 d0 = *(const int4*)(ei + NE + e0);
    const int4 d1 = *(const int4*)(ei + NE + e0 + 4);
    const int4 s0 = *(const int4*)(ei + e0);
    const int4 s1 = *(const int4*)(ei + e0 + 4);
    const int4 r0 = *(const int4*)(rank + e0);
    const int4 r1 = *(const int4*)(rank + e0 + 4);
    const int d[8] = {d0.x, d0.y, d0.z, d0.w, d1.x, d1.y, d1.z, d1.w};
    const int s[8] = {s0.x, s0.y, s0.z, s0.w, s1.x, s1.y, s1.z, s1.w};
    const int r[8] = {r0.x, r0.y, r0.z, r0.w, r1.x, r1.y, r1.z, r1.w};
#pragma unroll
    for (int k = 0; k < 8; ++k) {
        if ((unsigned)(d[k] - lo) < (unsigned)DPG)
            csr_src[row_ptr[d[k]] + r[k]] = s[k];
    }
}

// ----------------------------------------------------- gather aggregation ---
// one wave per dst node; 16-lane quarter owns an edge (4 edges in flight);
// lane owns 8 channels (one ushort8 = 16B load). Bound-shifted softmax.
__global__ __launch_bounds__(256) void k_agg(const int* __restrict__ row_ptr,
                                             const int* __restrict__ csr_src,
                                             const unsigned short* __restrict__ h_bf,
                                             const float* __restrict__ a_s,
                                             const float* __restrict__ a_d,
                                             const unsigned int* __restrict__ gmax,
                                             const float* __restrict__ bias,
                                             float* __restrict__ out) {
    const int n = blockIdx.x * 4 + (threadIdx.x >> 6);
    const int lane = threadIdx.x & 63;
    if (n >= NN) return;
    const int q = lane >> 4;                      // quarter: owns edges i+q
    const int ql = lane & 15;                     // channels 8*ql .. 8*ql+7
    const int hd = ql >> 2;                       // head of those channels
    const int beg = row_ptr[n];
    const int end = row_ptr[n + 1];

    const float ad_h = a_d[n * 4 + hd];
    const float bound = leaky(fdec(gmax[hd]) + ad_h);   // >= every edge score

    // self-loop at weight 0.25 per quarter (cross-quarter combine -> 1x)
    float ev = 0.25f * __expf(leaky(a_s[n * 4 + hd] + ad_h) - bound);
    float denom = ev;
    const u16x8 hs = *(const u16x8*)(h_bf + (size_t)n * HC + 8 * ql);
    float acc[8];
#pragma unroll
    for (int k = 0; k < 8; ++k) acc[k] = ev * bf2f(hs[k]);

    int i = beg + q;
    int s_next = (i < end) ? csr_src[i] : 0;
    for (; i < end; i += 4) {
        const int s = s_next;
        if (i + 4 < end) s_next = csr_src[i + 4];
        const float e = __expf(leaky(a_s[s * 4 + hd] + ad_h) - bound);
        const u16x8 hv = *(const u16x8*)(h_bf + (size_t)s * HC + 8 * ql);
        denom += e;
#pragma unroll
        for (int k = 0; k < 8; ++k)
            acc[k] = fmaf(e, bf2f(hv[k]), acc[k]);
    }
#pragma unroll
    for (int k = 0; k < 8; ++k) {
        acc[k] += __shfl_xor(acc[k], 16, 64);
        acc[k] += __shfl_xor(acc[k], 32, 64);
    }
    denom += __shfl_xor(denom, 16, 64);
    denom += __shfl_xor(denom, 32, 64);

    if (q == 0) {
        const float inv = 1.0f / (denom + EPS);
        float* o = out + (size_t)n * HC + 8 * ql;
        const float* b = bias + 8 * ql;
        float4 o0, o1;
        o0.x = acc[0] * inv + b[0]; o0.y = acc[1] * inv + b[1];
        o0.z = acc[2] * inv + b[2]; o0.w = acc[3] * inv + b[3];
        o1.x = acc[4] * inv + b[4]; o1.y = acc[5] * inv + b[5];
        o1.z = acc[6] * inv + b[6]; o1.w = acc[7] * inv + b[7];
        *(float4*)(o) = o0;
        *(float4*)(o + 4) = o1;
    }
}

// ---------------------------------------------------------------------------
extern "C" void kernel_launch(void* const* d_in, const int* in_sizes, int n_in,
                              void* d_out, int out_size, void* d_ws, size_t ws_size,
                              hipStream_t stream) {
    const float* x     = (const float*)d_in[0];
    const int*   ei    = (const int*)d_in[1];
    const float* W     = (const float*)d_in[2];
    const float* att_s = (const float*)d_in[3];
    const float* att_d = (const float*)d_in[4];
    const float* bias  = (const float*)d_in[5];
    float* out = (float*)d_out;

    char* ws = (char*)d_ws;
    int*   deg     = (int*)ws;    ws += (size_t)NN * PAD * 4;    // 3.2 MB padded
    int*   rank    = (int*)ws;    ws += (size_t)NE * 4;          // 6.4 MB
    int*   row_ptr = (int*)ws;    ws += 200016;                  // (NN+1) ints, 16B-rounded
    unsigned int* gmax = (unsigned int*)ws; ws += 64;
    int*   partial = (int*)ws;    ws += (size_t)SCAN_BLOCKS * 4; // 784 B
    int*   csr_src = (int*)ws;    ws += (size_t)NE * 4;          // 6.4 MB
    unsigned short* h_bf = (unsigned short*)ws; ws += (size_t)NN * HC * 2; // 12.8 MB
    float* a_s     = (float*)ws;  ws += (size_t)NN * HEADS * 4;
    float* a_d     = (float*)ws;  ws += (size_t)NN * HEADS * 4;
    unsigned short* Wt_bf = (unsigned short*)ws; ws += (size_t)IN_CH * HC * 2; // 32 KB

    hipMemsetAsync(deg, 0, (size_t)NN * PAD * 4, stream);
    k_init       <<<(IN_CH * HC + 255) / 256, 256, 0, stream>>>(gmax, W, Wt_bf);
    k_proj_count <<<PROJ_BLOCKS + COUNT_BLOCKS, 256, 0, stream>>>(
        x, Wt_bf, att_s, att_d, h_bf, a_s, a_d, ei, deg, rank);
    k_scan_part  <<<SCAN_BLOCKS, 256, 0, stream>>>(deg, a_s, partial, gmax);
    k_scan_top   <<<1, 256, 0, stream>>>(partial, row_ptr);
    k_scan_final <<<SCAN_BLOCKS, 256, 0, stream>>>(deg, partial, row_ptr);
    k_fill       <<<FILL_BPG * NGROUP, 256, 0, stream>>>(ei, rank, row_ptr, csr_src);
    k_agg        <<<(NN + 3) / 4, 256, 0, stream>>>(row_ptr, csr_src, h_bf, a_s, a_d,
                                                    gmax, bias, out);
}